// Round 6
// baseline (754.939 us; speedup 1.0000x reference)
//
#include <hip/hip_runtime.h>
#include <math.h>

// TopK router: logits = x @ W^T + b ; top-2 over E=64 ; sparse softmax.
// x: [T=16384, D=2048] f32, W: [64, 2048] f32, b: [64] f32.
// d_out: [T*64] router probs f32, then [T*2] top-k indices as f32.
//
// R6 = R5's proven structure with an occupancy push. R5: 4-way K-split,
// 34.8 KB LDS -> 4 blocks/CU = 16 waves/CU, VALUBusy 40%. Now: 8-way
// K-split (512-thr block, DQ=256), CK=32 chunks, LDS 36.9 KB -> still
// 4 blocks/CU but 8 waves each = 32 waves/CU (100%), VGPR forced <=64
// via __launch_bounds__(512,8) (compiler chose 64 unforced in R5).
// Per-32-float f32 fma chains identical to R5 (same k-order) -> index
// accuracy unchanged; f64 partial tree 4->8 terms (error ~1e-13).
// f64 partial combine done in two 8-token phases aliased into xs
// (32 KB <= 36.9 KB). Grid = 1024 = exactly 4 blocks/CU, no tail.
// Spill sentinel: WRITE_SIZE must stay ~4.2 MB.

#define RD 2048
#define RE 64
#define NW 8                    // waves per block (K-split factor)
#define TPB 16                  // tokens per block
#define DQ (RD / NW)            // 256 k-floats per wave
#define CK 32                   // k-floats staged per chunk
#define NC (DQ / CK)            // 8 chunks
#define ROWP 36                 // padded LDS row (floats)
#define BUFF (TPB * ROWP)       // floats per buffer

struct X2 { float4 a, b; };

__device__ __forceinline__ X2 ldx(const float* p) {
    X2 r;
    r.a = *(const float4*)(p + 0);
    r.b = *(const float4*)(p + 4);
    return r;
}
__device__ __forceinline__ void stx(float* p, const X2 r) {
    *(float4*)(p + 0) = r.a;
    *(float4*)(p + 4) = r.b;
}

// One chunk: 32 k-floats for all 16 tokens. Reads LDS buffer (C&1).
// fp32 fma chain of 8 float4s per token (identical arithmetic to R5's
// 32-float s-block), then one f64 accumulate per token.
#define COMPUTE_BODY(C) do {                                               \
    const float* xb_ = &xs[wq][(C) & 1][0][0];                             \
    const float4* wp_ = (const float4*)(wrow + (C) * CK);                  \
    const float4 w0_ = wp_[0], w1_ = wp_[1], w2_ = wp_[2], w3_ = wp_[3];   \
    const float4 w4_ = wp_[4], w5_ = wp_[5], w6_ = wp_[6], w7_ = wp_[7];   \
    _Pragma("unroll")                                                      \
    for (int tt_ = 0; tt_ < TPB; ++tt_) {                                  \
        const float4* xp_ = (const float4*)(xb_ + tt_ * ROWP);             \
        float4 a_;                                                         \
        a_.x = xp_[0].x * w0_.x; a_.y = xp_[0].y * w0_.y;                  \
        a_.z = xp_[0].z * w0_.z; a_.w = xp_[0].w * w0_.w;                  \
        a_.x = fmaf(xp_[1].x, w1_.x, a_.x); a_.y = fmaf(xp_[1].y, w1_.y, a_.y); \
        a_.z = fmaf(xp_[1].z, w1_.z, a_.z); a_.w = fmaf(xp_[1].w, w1_.w, a_.w); \
        a_.x = fmaf(xp_[2].x, w2_.x, a_.x); a_.y = fmaf(xp_[2].y, w2_.y, a_.y); \
        a_.z = fmaf(xp_[2].z, w2_.z, a_.z); a_.w = fmaf(xp_[2].w, w2_.w, a_.w); \
        a_.x = fmaf(xp_[3].x, w3_.x, a_.x); a_.y = fmaf(xp_[3].y, w3_.y, a_.y); \
        a_.z = fmaf(xp_[3].z, w3_.z, a_.z); a_.w = fmaf(xp_[3].w, w3_.w, a_.w); \
        a_.x = fmaf(xp_[4].x, w4_.x, a_.x); a_.y = fmaf(xp_[4].y, w4_.y, a_.y); \
        a_.z = fmaf(xp_[4].z, w4_.z, a_.z); a_.w = fmaf(xp_[4].w, w4_.w, a_.w); \
        a_.x = fmaf(xp_[5].x, w5_.x, a_.x); a_.y = fmaf(xp_[5].y, w5_.y, a_.y); \
        a_.z = fmaf(xp_[5].z, w5_.z, a_.z); a_.w = fmaf(xp_[5].w, w5_.w, a_.w); \
        a_.x = fmaf(xp_[6].x, w6_.x, a_.x); a_.y = fmaf(xp_[6].y, w6_.y, a_.y); \
        a_.z = fmaf(xp_[6].z, w6_.z, a_.z); a_.w = fmaf(xp_[6].w, w6_.w, a_.w); \
        a_.x = fmaf(xp_[7].x, w7_.x, a_.x); a_.y = fmaf(xp_[7].y, w7_.y, a_.y); \
        a_.z = fmaf(xp_[7].z, w7_.z, a_.z); a_.w = fmaf(xp_[7].w, w7_.w, a_.w); \
        dacc[tt_] += (double)((a_.x + a_.y) + (a_.z + a_.w));              \
    }                                                                      \
} while (0)

__global__ __launch_bounds__(512, 8) void topk_router_kernel(
    const float* __restrict__ x,
    const float* __restrict__ W,
    const float* __restrict__ b,
    float* __restrict__ out_router,
    float* __restrict__ out_idx,
    int total_tokens)
{
    const int lane = threadIdx.x & 63;
    const int wq = __builtin_amdgcn_readfirstlane((int)(threadIdx.x >> 6)); // K-eighth
    const int tok0 = blockIdx.x * TPB;

    // xs[wave][buf][token][ROWP]: 8*2*16*36*4 = 36864 B -> 4 blocks/CU.
    // Wave-private slices during the main loop (no barriers needed).
    // Reused as the f64 partial-combine buffer afterwards (32 KB needed).
    __shared__ __align__(16) float xs[NW][2][TPB][ROWP];

    // Staging: 4 lanes per token row; lane covers 8 floats (2 float4s).
    const int tmax = total_tokens - 1;
    const int stok = min(tok0 + (lane >> 2), tmax);
    const float* gsrc = x + (size_t)stok * RD + wq * DQ + (lane & 3) * 8;
    float* ldst = &xs[wq][0][lane >> 2][(lane & 3) * 8];
    const float* wrow = W + (size_t)lane * RD + wq * DQ;

    double dacc[TPB];
#pragma unroll
    for (int t = 0; t < TPB; ++t) dacc[t] = 0.0;

    // prologue: chunk 0 -> buf 0
    {
        X2 c0 = ldx(gsrc);
        stx(ldst, c0);
    }

    // main loop: issue chunk c+1 global loads early, compute c, write c+1 late
#pragma unroll 1
    for (int c = 0; c < NC - 1; ++c) {
        X2 nxt = ldx(gsrc + (c + 1) * CK);
        COMPUTE_BODY(c);
        stx(ldst + ((c + 1) & 1) * BUFF, nxt);
    }
    COMPUTE_BODY(NC - 1);

    // ---- two-phase f64 partial combine + epilogue (aliases xs) ----
    __syncthreads();
    double* pd = (double*)&xs[0][0][0][0];   // [8 tok][NW q][64 lanes] = 32 KB
    const double bias = (double)b[lane];

#pragma unroll 1
    for (int ph = 0; ph < 2; ++ph) {
        // write this phase's partials: tokens [ph*8, ph*8+8)
#pragma unroll
        for (int t8 = 0; t8 < 8; ++t8)
            pd[(size_t)(t8 * NW + wq) * RE + lane] = dacc[ph * 8 + t8];
        __syncthreads();

        // wave wq combines token tok0 + ph*8 + wq
        const int token = tok0 + ph * 8 + wq;
        double v = bias;
#pragma unroll
        for (int q = 0; q < NW; ++q)
            v += pd[(size_t)(wq * NW + q) * RE + lane];

        // argmax #1 (value desc, tie -> lower lane)
        double bestv = v;
        int besti = lane;
#pragma unroll
        for (int off = 32; off > 0; off >>= 1) {
            double ov = __shfl_xor(bestv, off, 64);
            int oi = __shfl_xor(besti, off, 64);
            if (ov > bestv || (ov == bestv && oi < besti)) { bestv = ov; besti = oi; }
        }

        // argmax #2 excluding winner
        double v2 = (lane == besti) ? -INFINITY : v;
        double best2v = v2;
        int best2i = lane;
#pragma unroll
        for (int off = 32; off > 0; off >>= 1) {
            double ov = __shfl_xor(best2v, off, 64);
            int oi = __shfl_xor(best2i, off, 64);
            if (ov > best2v || (ov == best2v && oi < best2i)) { best2v = ov; best2i = oi; }
        }

        // 2-element softmax; all other experts exactly 0
        const float e2 = expf((float)(best2v - bestv));
        const float denom = 1.0f + e2;
        const float p1v = 1.0f / denom;
        const float p2v = e2 / denom;

        if (token < total_tokens) {
            float outv = 0.0f;
            if (lane == besti) outv = p1v;
            else if (lane == best2i) outv = p2v;
            out_router[(size_t)token * RE + lane] = outv;
            if (lane == 0) {
                out_idx[(size_t)token * 2 + 0] = (float)besti;
                out_idx[(size_t)token * 2 + 1] = (float)best2i;
            }
        }
        __syncthreads();   // protect pd before next phase overwrites
    }
}

extern "C" void kernel_launch(void* const* d_in, const int* in_sizes, int n_in,
                              void* d_out, int out_size, void* d_ws, size_t ws_size,
                              hipStream_t stream) {
    const float* x = (const float*)d_in[0];
    const float* W = (const float*)d_in[1];
    const float* b = (const float*)d_in[2];

    const int E = in_sizes[2];                 // 64
    const int D = in_sizes[1] / E;             // 2048
    const int T = in_sizes[0] / D;             // 16384
    (void)E; (void)D;

    float* out_router = (float*)d_out;
    float* out_idx = out_router + (size_t)T * RE;

    const int grid = (T + TPB - 1) / TPB;      // 1024

    topk_router_kernel<<<grid, 512, 0, stream>>>(x, W, b, out_router, out_idx, T);
}

// Round 7
// 254.425 us; speedup vs baseline: 2.9672x; 2.9672x over previous
//
#include <hip/hip_runtime.h>
#include <math.h>

// TopK router: logits = x @ W^T + b ; top-2 over E=64 ; sparse softmax.
// x: [T=16384, D=2048] f32, W: [64, 2048] f32, b: [64] f32.
// d_out: [T*64] router probs f32, then [T*2] top-k indices as f32.
//
// R7: operand-role inversion. R5 was LDS-broadcast-bound: lane=expert made
// x (the 134 MB stream) a broadcast ds_read (16 useful B per ~10-cyc LDS
// issue -> ~120 us floor). Now lane=token: x is read per-lane (full 256 B
// per ds_read_b32, conflict-free via quad-XOR swizzle) and W (the tiny
// reused operand) is broadcast via s_load -> SGPRs (scalar pipe, free;
// v_fma v,s,v uses its 1 allowed SGPR). 8 waves/block, wave owns 8 experts
// -> LDS re-read volume 1.07 GB (~15 us), VALU becomes the floor (~27 us).
// Numerics: same 8-deep float4-slot f32 chains per 32-k + f64 accumulate
// as R5 (indices verified exact R1-R6). No launch-bounds squeeze (R6
// lesson): (512,2) caps nothing the kernel needs.
// Spill sentinel: WRITE_SIZE must stay ~4.2 MB.

#define RD 2048
#define RE 64
#define TB 64                   // tokens per block (= wave width)
#define CK 64                   // k-floats per chunk
#define NCH (RD / CK)           // 32 chunks
#define NWV 8                   // waves per block
#define EPW (RE / NWV)          // 8 experts per wave
#define BUFSZ (TB * CK)         // 4096 floats per buffer

// Swizzled LDS dword index for x-tile: k-major, tok XOR'd by quad-group.
// Write (fixed i, 64 staging lanes) and read (fixed k, 64 lanes) are both
// <=2-way bank patterns (free).
#define XIDX(k, tok) (((k) << 6) + ((tok) ^ ((((k) >> 2) & 7) << 2)))

__device__ __forceinline__ void put4(float* xb, int tok, int q, float4 v) {
    const int k0 = q << 2;
    xb[XIDX(k0 + 0, tok)] = v.x;
    xb[XIDX(k0 + 1, tok)] = v.y;
    xb[XIDX(k0 + 2, tok)] = v.z;
    xb[XIDX(k0 + 3, tok)] = v.w;
}

__global__ __launch_bounds__(512, 2) void topk_router_kernel(
    const float* __restrict__ x,
    const float* __restrict__ W,
    const float* __restrict__ b,
    float* __restrict__ out_router,
    float* __restrict__ out_idx,
    int total_tokens)
{
    const int tid = threadIdx.x;
    const int lane = tid & 63;
    const int wv = __builtin_amdgcn_readfirstlane(tid >> 6);   // 0..7
    const int tok0 = blockIdx.x * TB;

    __shared__ __align__(16) float xs[2][BUFSZ];   // 32 KB

    // Staging map: thread -> (token row, k-quad); 2 float4s per thread.
    const int stok = tid >> 4;          // 0..31
    const int sq   = tid & 15;          // 0..15
    const int tmax = total_tokens - 1;
    const int ga = min(tok0 + stok, tmax);
    const int gb = min(tok0 + stok + 32, tmax);
    const float* gsa = x + (size_t)ga * RD + sq * 4;
    const float* gsb = x + (size_t)gb * RD + sq * 4;

    const int e0 = wv * EPW;
    const float* wbase = W + (size_t)e0 * RD;   // wave-uniform -> s_load path

    double dacc[EPW];
#pragma unroll
    for (int j = 0; j < EPW; ++j) dacc[j] = 0.0;

    // prologue: chunk 0 -> buf 0
    {
        const float4 va = *(const float4*)gsa;
        const float4 vb = *(const float4*)gsb;
        put4(xs[0], stok, sq, va);
        put4(xs[0], stok + 32, sq, vb);
    }
    __syncthreads();

#pragma unroll 1
    for (int c = 0; c < NCH; ++c) {
        // issue next chunk's global loads early (write-late after barrier)
        float4 na, nb;
        const bool more = (c + 1 < NCH);
        if (more) {
            na = *(const float4*)(gsa + (size_t)(c + 1) * CK);
            nb = *(const float4*)(gsb + (size_t)(c + 1) * CK);
        }

        const float* xb = xs[c & 1];
        const float* wc = wbase + (size_t)c * CK;

        // compute chunk c: two 32-k halves; lane = token, experts j=0..7
#pragma unroll
        for (int h = 0; h < 2; ++h) {
            float ch[EPW][4];
#pragma unroll
            for (int j = 0; j < EPW; ++j) {
                ch[j][0] = 0.0f; ch[j][1] = 0.0f;
                ch[j][2] = 0.0f; ch[j][3] = 0.0f;
            }
#pragma unroll
            for (int q = 0; q < 8; ++q) {
                const int kk = h * 32 + q * 4;
                const float xk0 = xb[XIDX(kk + 0, lane)];
                const float xk1 = xb[XIDX(kk + 1, lane)];
                const float xk2 = xb[XIDX(kk + 2, lane)];
                const float xk3 = xb[XIDX(kk + 3, lane)];
#pragma unroll
                for (int j = 0; j < EPW; ++j) {
                    const float4 w4 = *(const float4*)(wc + (size_t)j * RD + kk);
                    ch[j][0] = fmaf(xk0, w4.x, ch[j][0]);
                    ch[j][1] = fmaf(xk1, w4.y, ch[j][1]);
                    ch[j][2] = fmaf(xk2, w4.z, ch[j][2]);
                    ch[j][3] = fmaf(xk3, w4.w, ch[j][3]);
                }
            }
#pragma unroll
            for (int j = 0; j < EPW; ++j)
                dacc[j] += (double)((ch[j][0] + ch[j][1]) + (ch[j][2] + ch[j][3]));
        }

        __syncthreads();                 // everyone done reading buf (c-1)&1^... (all reads of c done)
        if (more) {
            put4(xs[(c + 1) & 1], stok, sq, na);
            put4(xs[(c + 1) & 1], stok + 32, sq, nb);
        }
        __syncthreads();                 // next buffer visible
    }

    // ---- exchange logits (f64) through retired x buffer, XOR-swizzled ----
    double* lg = (double*)&xs[0][0];     // [64 tok][64 e] doubles = 32 KB
#pragma unroll
    for (int j = 0; j < EPW; ++j)
        lg[(size_t)lane * 64 + ((e0 + j) ^ (lane & 31))] = dacc[j];
    __syncthreads();

    const double bias = (double)b[lane];

    // epilogue: wave wv handles tokens [wv*8, wv*8+8); lane = expert
#pragma unroll 1
    for (int tt = 0; tt < TB / NWV; ++tt) {
        const int t = wv * (TB / NWV) + tt;
        const int token = tok0 + t;
        const double v = lg[(size_t)t * 64 + (lane ^ (t & 31))] + bias;

        // argmax #1 (value desc, tie -> lower lane)
        double bestv = v;
        int besti = lane;
#pragma unroll
        for (int off = 32; off > 0; off >>= 1) {
            double ov = __shfl_xor(bestv, off, 64);
            int oi = __shfl_xor(besti, off, 64);
            if (ov > bestv || (ov == bestv && oi < besti)) { bestv = ov; besti = oi; }
        }

        // argmax #2 excluding winner
        double v2 = (lane == besti) ? -INFINITY : v;
        double best2v = v2;
        int best2i = lane;
#pragma unroll
        for (int off = 32; off > 0; off >>= 1) {
            double ov = __shfl_xor(best2v, off, 64);
            int oi = __shfl_xor(best2i, off, 64);
            if (ov > best2v || (ov == best2v && oi < best2i)) { best2v = ov; best2i = oi; }
        }

        // 2-element softmax; all other experts exactly 0
        const float e2 = expf((float)(best2v - bestv));
        const float denom = 1.0f + e2;
        const float p1v = 1.0f / denom;
        const float p2v = e2 / denom;

        if (token < total_tokens) {
            float outv = 0.0f;
            if (lane == besti) outv = p1v;
            else if (lane == best2i) outv = p2v;
            out_router[(size_t)token * RE + lane] = outv;
            if (lane == 0) {
                out_idx[(size_t)token * 2 + 0] = (float)besti;
                out_idx[(size_t)token * 2 + 1] = (float)best2i;
            }
        }
    }
}

extern "C" void kernel_launch(void* const* d_in, const int* in_sizes, int n_in,
                              void* d_out, int out_size, void* d_ws, size_t ws_size,
                              hipStream_t stream) {
    const float* x = (const float*)d_in[0];
    const float* W = (const float*)d_in[1];
    const float* b = (const float*)d_in[2];

    const int E = in_sizes[2];                 // 64
    const int D = in_sizes[1] / E;             // 2048
    const int T = in_sizes[0] / D;             // 16384
    (void)E; (void)D;

    float* out_router = (float*)d_out;
    float* out_idx = out_router + (size_t)T * RE;

    const int grid = (T + TB - 1) / TB;        // 256

    topk_router_kernel<<<grid, 512, 0, stream>>>(x, W, b, out_router, out_idx, T);
}